// Round 5
// baseline (390.862 us; speedup 1.0000x reference)
//
#include <hip/hip_runtime.h>
#include <hip/hip_bf16.h>
#include <stdint.h>

#define N_NODES 100000
#define N_EDGES 300000
#define HID 256
#define NB_SCAN 98   // ceil(100000/1024)

typedef unsigned short u16;
typedef unsigned int u32;
typedef __attribute__((ext_vector_type(8))) short short8;
typedef __attribute__((ext_vector_type(4))) float f32x4;

__device__ __forceinline__ float bf2f(u16 u) {
    union { u32 i; float f; } c; c.i = ((u32)u) << 16; return c.f;
}
__device__ __forceinline__ u16 f2bf(float f) {
    union { float f; u32 i; } c; c.f = f;
    u32 x = c.i;
    u32 r = (x + 0x7fffu + ((x >> 16) & 1u)) >> 16;  // round-nearest-even
    return (u16)r;
}
__device__ __forceinline__ u32 pk2(float lo, float hi) {
    return (u32)f2bf(lo) | ((u32)f2bf(hi) << 16);
}
__device__ __forceinline__ void unpack8(uint4 u, float* f) {
    f[0] = bf2f(u.x & 0xffffu); f[1] = bf2f(u.x >> 16);
    f[2] = bf2f(u.y & 0xffffu); f[3] = bf2f(u.y >> 16);
    f[4] = bf2f(u.z & 0xffffu); f[5] = bf2f(u.z >> 16);
    f[6] = bf2f(u.w & 0xffffu); f[7] = bf2f(u.w >> 16);
}

// ---------------- CSR build ----------------
__global__ void icnt_k(const int* __restrict__ dst, int* __restrict__ icnt) {
    int e = blockIdx.x * blockDim.x + threadIdx.x;
    if (e < N_EDGES) atomicAdd(&icnt[dst[e]], 1);
}

__global__ void scan1_k(const int* __restrict__ icnt, int* __restrict__ off,
                        int* __restrict__ bsum) {
    __shared__ int sh[256];
    int t = threadIdx.x;
    int base = blockIdx.x * 1024 + t * 4;
    int v[4];
    #pragma unroll
    for (int j = 0; j < 4; ++j) {
        int idx = base + j;
        v[j] = (idx < N_NODES) ? icnt[idx] : 0;
    }
    int s = v[0] + v[1] + v[2] + v[3];
    sh[t] = s;
    __syncthreads();
    #pragma unroll
    for (int d = 1; d < 256; d <<= 1) {
        int x = (t >= d) ? sh[t - d] : 0;
        __syncthreads();
        if (t >= d) sh[t] += x;
        __syncthreads();
    }
    int excl = sh[t] - s;
    #pragma unroll
    for (int j = 0; j < 4; ++j) {
        int idx = base + j;
        if (idx < N_NODES) off[idx] = excl;
        excl += v[j];
    }
    if (t == 255) bsum[blockIdx.x] = sh[255];
}

__global__ void scan2_k(int* __restrict__ bsum) {
    __shared__ int sh[128];
    int t = threadIdx.x;
    int v = (t < NB_SCAN) ? bsum[t] : 0;
    sh[t] = v;
    __syncthreads();
    #pragma unroll
    for (int d = 1; d < 128; d <<= 1) {
        int x = (t >= d) ? sh[t - d] : 0;
        __syncthreads();
        if (t >= d) sh[t] += x;
        __syncthreads();
    }
    if (t < NB_SCAN) bsum[t] = sh[t] - v;
}

__global__ void scan3_k(int* __restrict__ off, int* __restrict__ pos,
                        const int* __restrict__ bsum) {
    int idx = blockIdx.x * blockDim.x + threadIdx.x;
    if (idx < N_NODES) {
        int o = off[idx] + bsum[idx >> 10];
        off[idx] = o;
        pos[idx] = o;
    }
}

__global__ void scat_k(const int* __restrict__ src, const int* __restrict__ dst,
                       int* __restrict__ pos, int* __restrict__ csrc) {
    int e = blockIdx.x * blockDim.x + threadIdx.x;
    if (e < N_EDGES) {
        int slot = atomicAdd(&pos[dst[e]], 1);
        csrc[slot] = src[e];
    }
}

// ---------------- CSR mean aggregation: 32 lanes per node ----------------
__global__ void aggc_k(const u16* __restrict__ x, const int* __restrict__ off,
                       const int* __restrict__ pos, const int* __restrict__ csrc,
                       u16* __restrict__ mean) {
    int node = blockIdx.x * (blockDim.x >> 5) + (threadIdx.x >> 5);
    if (node >= N_NODES) return;
    int lane = threadIdx.x & 31;
    int s = off[node], e = pos[node];
    float acc[8] = {0.f, 0.f, 0.f, 0.f, 0.f, 0.f, 0.f, 0.f};
    for (int i = s; i < e; ++i) {
        int sr = csrc[i];
        uint4 u = *(const uint4*)(x + (size_t)sr * HID + lane * 8);
        float f[8];
        unpack8(u, f);
        #pragma unroll
        for (int j = 0; j < 8; ++j) acc[j] += f[j];
    }
    float inv = 1.0f / fmaxf((float)(e - s), 1.0f);
    uint4 r;
    r.x = pk2(acc[0] * inv, acc[1] * inv);
    r.y = pk2(acc[2] * inv, acc[3] * inv);
    r.z = pk2(acc[4] * inv, acc[5] * inv);
    r.w = pk2(acc[6] * inv, acc[7] * inv);
    *(uint4*)(mean + (size_t)node * HID + lane * 8) = r;
}

// ---------------- conversions ----------------
__global__ void cvt_x_k(const float* __restrict__ x, u16* __restrict__ xb) {
    int i = blockIdx.x * blockDim.x + threadIdx.x;
    float4 v = ((const float4*)x)[i];
    uint2 r; r.x = pk2(v.x, v.y); r.y = pk2(v.z, v.w);
    ((uint2*)xb)[i] = r;
}

__global__ void wt_k(const float* __restrict__ Wl, const float* __restrict__ Wr,
                     u16* __restrict__ Bt, int K1, int LK, int N, int total) {
    int t = blockIdx.x * blockDim.x + threadIdx.x;
    if (t >= total) return;
    int n = t >> LK;
    int k = t & ((1 << LK) - 1);
    float v = (k < K1) ? Wl[(size_t)k * N + n] : Wr[(size_t)(k - K1) * N + n];
    Bt[t] = f2bf(v);
}

// ---------------- MFMA GEMM, both operands double-buffered & 1-step prefetched ----
// BK=32 (64B rows). Per step kc: issue A(kc+1)+B(kc+1) into alt buffers,
// s_waitcnt vmcnt(AI+BI) -> waits only for tiles issued one step earlier,
// s_barrier, ds_read+MFMA, s_barrier.
// LDS 64B rows, 4x16B slots, XOR swizzle: slot ^= (row&3)^((row>>2)&3).
template<int KC, int SPLIT, int MODE, int BN, int THREADS>
__launch_bounds__(THREADS)
__global__ void mgemm_k(const u16* __restrict__ A1, const u16* __restrict__ A2,
                        int ldaB,
                        const u16* __restrict__ Bt,
                        const float* __restrict__ bias,
                        const u16* __restrict__ inp,
                        u16* __restrict__ outb, u16* __restrict__ outb2,
                        float* __restrict__ outf) {
    constexpr int W   = THREADS / 64;
    constexpr int WNW = W / 2;
    constexpr int WN  = BN / WNW;
    constexpr int NFC = WN / 16;
    constexpr int ATB = 128 * 64;              // A tile bytes (128 rows x 64B)
    constexpr int BTB = BN * 64;               // B tile bytes
    constexpr int AI  = ATB / (THREADS * 16);  // A issues/thread
    constexpr int BI  = BTB / (THREADS * 16);  // B issues/thread
    constexpr int BTROW = KC * 64;             // Bt row stride in bytes (K*2)
    __shared__ char lds[2 * ATB + 2 * BTB];

    const int tid  = threadIdx.x;
    const int lane = tid & 63;
    const int wid  = tid >> 6;
    const int wr   = wid & 1;
    const int wc   = wid >> 1;
    const int r0   = blockIdx.x * 128;

    f32x4 acc[4][NFC];
    #pragma unroll
    for (int m = 0; m < 4; ++m)
        #pragma unroll
        for (int n = 0; n < NFC; ++n) acc[m][n] = (f32x4)(0.f);

    // staging: chunk = 1KB = 16 rows of 64B; lane covers row lane>>2, slot lane&3
    const int crow = lane >> 2;
    // swizzle key for a row r: (r&3)^((r>>2)&3); for staged row: crow-based
    const int skey  = ((lane >> 2) & 3) ^ ((lane >> 4) & 3);
    const int sslot = ((lane & 3) ^ skey) << 4;   // source 16B-slot byte offset

    auto stage = [&](int kc, int buf) {
        const u16* Ag = (kc < SPLIT) ? A1 : A2;
        const int  kb = ((kc < SPLIT) ? kc : kc - SPLIT) * 64;   // byte offset in A row
        char* Ad = lds + buf * ATB;
        #pragma unroll
        for (int i = 0; i < AI; ++i) {
            const int ch = i * W + wid;
            int rg = r0 + ch * 16 + crow;
            rg = (rg < N_NODES) ? rg : (N_NODES - 1);
            const char* g = (const char*)Ag + (size_t)rg * ldaB + kb + sslot;
            __builtin_amdgcn_global_load_lds(
                (__attribute__((address_space(1))) void*)g,
                (__attribute__((address_space(3))) void*)(Ad + ch * 1024 + (lane & 3) * 16 + crow * 64),
                16, 0, 0);
        }
        char* Bd = lds + 2 * ATB + buf * BTB;
        #pragma unroll
        for (int i = 0; i < BI; ++i) {
            const int ch = i * W + wid;
            const int nt = ch * 16 + crow;
            const char* g = (const char*)Bt + (size_t)nt * BTROW + kc * 64 + sslot;
            __builtin_amdgcn_global_load_lds(
                (__attribute__((address_space(1))) void*)g,
                (__attribute__((address_space(3))) void*)(Bd + ch * 1024 + (lane & 3) * 16 + crow * 64),
                16, 0, 0);
        }
    };

    stage(0, 0);
    // frag-read swizzled slot byte offset (constant across frags)
    const int q = (((lane >> 4) ^ (lane & 3) ^ ((lane >> 2) & 3)) << 4);

    for (int kc = 0; kc < KC; ++kc) {
        const int cur = kc & 1;
        if (kc + 1 < KC) {
            stage(kc + 1, cur ^ 1);
            asm volatile("s_waitcnt vmcnt(%0)" :: "i"(AI + BI) : "memory");
        } else {
            asm volatile("s_waitcnt vmcnt(0)" ::: "memory");
        }
        __builtin_amdgcn_s_barrier();
        __builtin_amdgcn_sched_barrier(0);

        const char* Ab = lds + cur * ATB;
        const char* Bb = lds + 2 * ATB + cur * BTB;
        short8 af[4], bv[NFC];
        #pragma unroll
        for (int m = 0; m < 4; ++m)
            af[m] = *(const short8*)(Ab + (wr * 64 + m * 16 + (lane & 15)) * 64 + q);
        #pragma unroll
        for (int n = 0; n < NFC; ++n)
            bv[n] = *(const short8*)(Bb + (wc * WN + n * 16 + (lane & 15)) * 64 + q);
        #pragma unroll
        for (int m = 0; m < 4; ++m)
            #pragma unroll
            for (int n = 0; n < NFC; ++n)
                acc[m][n] = __builtin_amdgcn_mfma_f32_16x16x32_bf16(
                    af[m], bv[n], acc[m][n], 0, 0, 0);
        asm volatile("" ::: "memory");
        __builtin_amdgcn_s_barrier();
    }

    // ---- epilogue ----
    const int er = (lane >> 4) * 4;
    const int ec = lane & 15;
    #pragma unroll
    for (int m = 0; m < 4; ++m) {
        #pragma unroll
        for (int n = 0; n < NFC; ++n) {
            const int col = wc * WN + n * 16 + ec;
            const float bvv = bias[col];
            f32x4 v = acc[m][n];
            #pragma unroll
            for (int r = 0; r < 4; ++r) {
                const int row = r0 + wr * 64 + m * 16 + er + r;
                if (row >= N_NODES) continue;
                float s = v[r] + bvv;
                if constexpr (MODE == 0) {
                    outb2[(size_t)row * HID + col] = f2bf(s);
                    outb [(size_t)row * HID + col] = f2bf(fmaxf(s, 0.f));
                } else if constexpr (MODE == 1) {
                    float ip = bf2f(inp[(size_t)row * HID + col]);
                    outb[(size_t)row * HID + col] = f2bf(fmaxf(s, 0.f) + 0.2f * ip);
                } else {
                    outf[(size_t)row * 64 + col] = s;
                }
            }
        }
    }
}

// ---------------- in-place log_softmax over 64 cols, one wave per row ----------------
__global__ void lsm_k(float* __restrict__ out) {
    int r = blockIdx.x * 4 + (threadIdx.x >> 6);
    int lane = threadIdx.x & 63;
    if (r >= N_NODES) return;
    float v = out[(size_t)r * 64 + lane];
    float m = v;
    #pragma unroll
    for (int off = 32; off; off >>= 1) m = fmaxf(m, __shfl_xor(m, off));
    float s = expf(v - m);
    #pragma unroll
    for (int off = 32; off; off >>= 1) s += __shfl_xor(s, off);
    out[(size_t)r * 64 + lane] = (v - m) - logf(s);
}

extern "C" void kernel_launch(void* const* d_in, const int* in_sizes, int n_in,
                              void* d_out, int out_size, void* d_ws, size_t ws_size,
                              hipStream_t stream) {
    const float* x    = (const float*)d_in[0];
    const int*   ei   = (const int*)d_in[1];
    const float* W_in = (const float*)d_in[2];
    const float* b_in = (const float*)d_in[3];
    const float* Wl1  = (const float*)d_in[4];
    const float* bl1  = (const float*)d_in[5];
    const float* Wr1  = (const float*)d_in[6];
    const float* Wl2  = (const float*)d_in[7];
    const float* bl2  = (const float*)d_in[8];
    const float* Wr2  = (const float*)d_in[9];
    const float* Wl3  = (const float*)d_in[10];
    const float* bl3  = (const float*)d_in[11];
    const float* Wr3  = (const float*)d_in[12];
    float* out = (float*)d_out;

    const int* esrc = ei;
    const int* edst = ei + N_EDGES;

    char* ws = (char*)d_ws;
    u16* inp  = (u16*)(ws + 0);             // 51,200,000
    u16* xA   = (u16*)(ws + 51200000);      // 51,200,000
    u16* xB   = (u16*)(ws + 102400000);     // 51,200,000
    u16* mean = (u16*)(ws + 153600000);     // 51,200,000
    u16* xbf  = (u16*)(ws + 204800000);     // 25,600,000
    u16* BtIn = (u16*)(ws + 230400000);     // 65,536
    u16* Bt1  = (u16*)(ws + 230465536);     // 262,144
    u16* Bt2  = (u16*)(ws + 230727680);     // 262,144
    u16* Bt3  = (u16*)(ws + 230989824);     // 65,536
    int* icnt = (int*)(ws + 231055360);     // 400,000
    int* coff = (int*)(ws + 231455360);     // 400,000
    int* cpos = (int*)(ws + 231855360);     // 400,000
    int* csrc = (int*)(ws + 232255360);     // 1,200,000
    int* bsum = (int*)(ws + 233455360);     // 512

    dim3 blk(256);
    dim3 gE((N_EDGES + 255) / 256);
    dim3 gN((N_NODES + 255) / 256);
    dim3 gAgg((N_NODES + 7) / 8);
    dim3 gG((N_NODES + 127) / 128);         // 782

    // ---- CSR build ----
    hipMemsetAsync(icnt, 0, (size_t)N_NODES * 4, stream);
    icnt_k<<<gE, blk, 0, stream>>>(edst, icnt);
    scan1_k<<<NB_SCAN, blk, 0, stream>>>(icnt, coff, bsum);
    scan2_k<<<1, 128, 0, stream>>>(bsum);
    scan3_k<<<gN, blk, 0, stream>>>(coff, cpos, bsum);
    scat_k<<<gE, blk, 0, stream>>>(esrc, edst, cpos, csrc);

    // ---- conversions ----
    cvt_x_k<<<(N_NODES * 128 / 4 + 255) / 256, blk, 0, stream>>>(x, xbf);
    wt_k<<<(256 * 128 + 255) / 256, blk, 0, stream>>>(W_in, W_in, BtIn, 128, 7, 256, 256 * 128);
    wt_k<<<(256 * 512 + 255) / 256, blk, 0, stream>>>(Wl1, Wr1, Bt1, 256, 9, 256, 256 * 512);
    wt_k<<<(256 * 512 + 255) / 256, blk, 0, stream>>>(Wl2, Wr2, Bt2, 256, 9, 256, 256 * 512);
    wt_k<<<(64 * 512 + 255) / 256, blk, 0, stream>>>(Wl3, Wr3, Bt3, 256, 9, 64, 64 * 512);

    // ---- input: H0 = x @ W_in + b_in ; inp = H0, xA = relu(H0) ----
    mgemm_k<4, 4, 0, 256, 512><<<gG, 512, 0, stream>>>(
        xbf, xbf, 256, BtIn, b_in, nullptr, xA, inp, nullptr);

    // ---- layer 1 ----
    aggc_k<<<gAgg, blk, 0, stream>>>(xA, coff, cpos, csrc, mean);
    mgemm_k<16, 8, 1, 256, 512><<<gG, 512, 0, stream>>>(
        mean, xA, 512, Bt1, bl1, inp, xB, nullptr, nullptr);

    // ---- layer 2 ----
    aggc_k<<<gAgg, blk, 0, stream>>>(xB, coff, cpos, csrc, mean);
    mgemm_k<16, 8, 1, 256, 512><<<gG, 512, 0, stream>>>(
        mean, xB, 512, Bt2, bl2, inp, xA, nullptr, nullptr);

    // ---- layer 3 ----
    aggc_k<<<gAgg, blk, 0, stream>>>(xA, coff, cpos, csrc, mean);
    mgemm_k<16, 8, 2, 64, 256><<<gG, blk, 0, stream>>>(
        mean, xA, 512, Bt3, bl3, nullptr, nullptr, nullptr, out);

    // ---- log_softmax in place ----
    lsm_k<<<N_NODES / 4, blk, 0, stream>>>(out);
}

// Round 6
// 339.844 us; speedup vs baseline: 1.1501x; 1.1501x over previous
//
#include <hip/hip_runtime.h>
#include <hip/hip_bf16.h>
#include <stdint.h>

#define N_NODES 100000
#define N_EDGES 300000
#define HID 256
#define NB_SCAN 98   // ceil(100000/1024)

typedef unsigned short u16;
typedef unsigned int u32;
typedef __attribute__((ext_vector_type(8))) short short8;
typedef __attribute__((ext_vector_type(4))) float f32x4;

__device__ __forceinline__ float bf2f(u16 u) {
    union { u32 i; float f; } c; c.i = ((u32)u) << 16; return c.f;
}
__device__ __forceinline__ u16 f2bf(float f) {
    union { float f; u32 i; } c; c.f = f;
    u32 x = c.i;
    u32 r = (x + 0x7fffu + ((x >> 16) & 1u)) >> 16;  // round-nearest-even
    return (u16)r;
}
__device__ __forceinline__ u32 pk2(float lo, float hi) {
    return (u32)f2bf(lo) | ((u32)f2bf(hi) << 16);
}
__device__ __forceinline__ void unpack8(uint4 u, float* f) {
    f[0] = bf2f(u.x & 0xffffu); f[1] = bf2f(u.x >> 16);
    f[2] = bf2f(u.y & 0xffffu); f[3] = bf2f(u.y >> 16);
    f[4] = bf2f(u.z & 0xffffu); f[5] = bf2f(u.z >> 16);
    f[6] = bf2f(u.w & 0xffffu); f[7] = bf2f(u.w >> 16);
}

// ---------------- CSR build ----------------
__global__ void icnt_k(const int* __restrict__ dst, int* __restrict__ icnt) {
    int e = blockIdx.x * blockDim.x + threadIdx.x;
    if (e < N_EDGES) atomicAdd(&icnt[dst[e]], 1);
}

__global__ void scan1_k(const int* __restrict__ icnt, int* __restrict__ off,
                        int* __restrict__ bsum) {
    __shared__ int sh[256];
    int t = threadIdx.x;
    int base = blockIdx.x * 1024 + t * 4;
    int v[4];
    #pragma unroll
    for (int j = 0; j < 4; ++j) {
        int idx = base + j;
        v[j] = (idx < N_NODES) ? icnt[idx] : 0;
    }
    int s = v[0] + v[1] + v[2] + v[3];
    sh[t] = s;
    __syncthreads();
    #pragma unroll
    for (int d = 1; d < 256; d <<= 1) {
        int x = (t >= d) ? sh[t - d] : 0;
        __syncthreads();
        if (t >= d) sh[t] += x;
        __syncthreads();
    }
    int excl = sh[t] - s;
    #pragma unroll
    for (int j = 0; j < 4; ++j) {
        int idx = base + j;
        if (idx < N_NODES) off[idx] = excl;
        excl += v[j];
    }
    if (t == 255) bsum[blockIdx.x] = sh[255];
}

__global__ void scan2_k(int* __restrict__ bsum) {
    __shared__ int sh[128];
    int t = threadIdx.x;
    int v = (t < NB_SCAN) ? bsum[t] : 0;
    sh[t] = v;
    __syncthreads();
    #pragma unroll
    for (int d = 1; d < 128; d <<= 1) {
        int x = (t >= d) ? sh[t - d] : 0;
        __syncthreads();
        if (t >= d) sh[t] += x;
        __syncthreads();
    }
    if (t < NB_SCAN) bsum[t] = sh[t] - v;
}

__global__ void scan3_k(int* __restrict__ off, int* __restrict__ pos,
                        const int* __restrict__ bsum) {
    int idx = blockIdx.x * blockDim.x + threadIdx.x;
    if (idx < N_NODES) {
        int o = off[idx] + bsum[idx >> 10];
        off[idx] = o;
        pos[idx] = o;
    }
}

__global__ void scat_k(const int* __restrict__ src, const int* __restrict__ dst,
                       int* __restrict__ pos, int* __restrict__ csrc) {
    int e = blockIdx.x * blockDim.x + threadIdx.x;
    if (e < N_EDGES) {
        int slot = atomicAdd(&pos[dst[e]], 1);
        csrc[slot] = src[e];
    }
}

// ---------------- CSR mean aggregation: 32 lanes per node ----------------
__global__ void aggc_k(const u16* __restrict__ x, const int* __restrict__ off,
                       const int* __restrict__ pos, const int* __restrict__ csrc,
                       u16* __restrict__ mean) {
    int node = blockIdx.x * (blockDim.x >> 5) + (threadIdx.x >> 5);
    if (node >= N_NODES) return;
    int lane = threadIdx.x & 31;
    int s = off[node], e = pos[node];
    float acc[8] = {0.f, 0.f, 0.f, 0.f, 0.f, 0.f, 0.f, 0.f};
    for (int i = s; i < e; ++i) {
        int sr = csrc[i];
        uint4 u = *(const uint4*)(x + (size_t)sr * HID + lane * 8);
        float f[8];
        unpack8(u, f);
        #pragma unroll
        for (int j = 0; j < 8; ++j) acc[j] += f[j];
    }
    float inv = 1.0f / fmaxf((float)(e - s), 1.0f);
    uint4 r;
    r.x = pk2(acc[0] * inv, acc[1] * inv);
    r.y = pk2(acc[2] * inv, acc[3] * inv);
    r.z = pk2(acc[4] * inv, acc[5] * inv);
    r.w = pk2(acc[6] * inv, acc[7] * inv);
    *(uint4*)(mean + (size_t)node * HID + lane * 8) = r;
}

// ---------------- conversions ----------------
__global__ void cvt_x_k(const float* __restrict__ x, u16* __restrict__ xb) {
    int i = blockIdx.x * blockDim.x + threadIdx.x;
    float4 v = ((const float4*)x)[i];
    uint2 r; r.x = pk2(v.x, v.y); r.y = pk2(v.z, v.w);
    ((uint2*)xb)[i] = r;
}

__global__ void wt_k(const float* __restrict__ Wl, const float* __restrict__ Wr,
                     u16* __restrict__ Bt, int K1, int LK, int N, int total) {
    int t = blockIdx.x * blockDim.x + threadIdx.x;
    if (t >= total) return;
    int n = t >> LK;
    int k = t & ((1 << LK) - 1);
    float v = (k < K1) ? Wl[(size_t)k * N + n] : Wr[(size_t)(k - K1) * N + n];
    Bt[t] = f2bf(v);
}

// ---------------- MFMA GEMM (m97 shape: 256 thr, 32KB LDS, 2-barrier) ------
// Tile 128 x BN, BK=64. 4 waves as 2(M) x 2(N); wave tile 64 x BN/2.
// A = A1 (K-chunks < SPLIT) then A2, both bf16 row stride ldaB bytes.
// Bt: bf16 [Ncols][KC*64] row-major (row stride KC*128 bytes).
// Epilogue staged through LDS (two 64-row halves) for coalesced uint4 I/O.
// MODE 0: v=acc+bias; outb2=bf16(v), outb=bf16(relu(v)).
// MODE 1: v=relu(acc+bias)+0.2*inp; outb=bf16(v).
// MODE 2: v=acc+bias; outf[row*64+col]=v.
template<int KC, int SPLIT, int MODE, int BN>
__launch_bounds__(256, 4)
__global__ void mgemm_k(const u16* __restrict__ A1, const u16* __restrict__ A2,
                        int ldaB,
                        const u16* __restrict__ Bt,
                        const float* __restrict__ bias,
                        const u16* __restrict__ inp,
                        u16* __restrict__ outb, u16* __restrict__ outb2,
                        float* __restrict__ outf) {
    constexpr int WN  = BN / 2;          // cols per wave
    constexpr int NFC = WN / 16;         // 16-col frags per wave
    constexpr int ASZ = 128 * 128;       // A tile bytes (128 rows x 128B)
    constexpr int BSZ = BN * 128;        // B tile bytes
    constexpr int EPL = 64 * BN * 4;     // epilogue half-tile (f32)
    constexpr int LSZ = (ASZ + BSZ > EPL) ? (ASZ + BSZ) : EPL;
    constexpr int BI  = BN / 32;         // B issues per thread
    __shared__ char lds[LSZ];

    const int tid  = threadIdx.x;
    const int lane = tid & 63;
    const int wid  = tid >> 6;           // 0..3
    const int wr   = wid >> 1;           // M half
    const int wc   = wid & 1;            // N half
    const int r0   = blockIdx.x * 128;
    const int c0   = blockIdx.y * BN;

    f32x4 acc[4][NFC];
    #pragma unroll
    for (int m = 0; m < 4; ++m)
        #pragma unroll
        for (int n = 0; n < NFC; ++n) acc[m][n] = (f32x4)(0.f);

    // pre-swizzled source slot: slot = (lane&7) ^ (row&7); row&7 == lane>>3
    const int sslot = (((lane & 7) ^ (lane >> 3)) << 4);
    const int lrow  = lane >> 3;

    for (int kc = 0; kc < KC; ++kc) {
        // ---- stage A tile [128 x 128B] : 4 issues/thread ----
        {
            const u16* Ag = (kc < SPLIT) ? A1 : A2;
            const int  kb = ((kc < SPLIT) ? kc : kc - SPLIT) * 128;
            #pragma unroll
            for (int i = 0; i < 4; ++i) {
                const int rb = wid * 32 + i * 8;
                int rg = r0 + rb + lrow;
                rg = (rg < N_NODES) ? rg : (N_NODES - 1);
                const char* g = (const char*)Ag + (size_t)rg * ldaB + kb + sslot;
                __builtin_amdgcn_global_load_lds(
                    (__attribute__((address_space(1))) void*)g,
                    (__attribute__((address_space(3))) void*)(lds + rb * 128),
                    16, 0, 0);
            }
        }
        // ---- stage B tile [BN x 128B] : BI issues/thread ----
        #pragma unroll
        for (int i = 0; i < BI; ++i) {
            const int nb = wid * (BN / 4) + i * 8;
            const int nt = c0 + nb + lrow;
            const char* g = (const char*)Bt + (size_t)nt * (KC * 128) + kc * 128 + sslot;
            __builtin_amdgcn_global_load_lds(
                (__attribute__((address_space(1))) void*)g,
                (__attribute__((address_space(3))) void*)(lds + ASZ + nb * 128),
                16, 0, 0);
        }
        __syncthreads();

        // ---- compute ----
        #pragma unroll
        for (int ks = 0; ks < 2; ++ks) {
            const int q = ((ks * 4 + (lane >> 4)) ^ (lane & 7)) << 4;
            short8 af[4], bv[NFC];
            #pragma unroll
            for (int m = 0; m < 4; ++m)
                af[m] = *(const short8*)(lds + (wr * 64 + m * 16 + (lane & 15)) * 128 + q);
            #pragma unroll
            for (int n = 0; n < NFC; ++n)
                bv[n] = *(const short8*)(lds + ASZ + (wc * WN + n * 16 + (lane & 15)) * 128 + q);
            #pragma unroll
            for (int m = 0; m < 4; ++m)
                #pragma unroll
                for (int n = 0; n < NFC; ++n)
                    acc[m][n] = __builtin_amdgcn_mfma_f32_16x16x32_bf16(
                        af[m], bv[n], acc[m][n], 0, 0, 0);
        }
        __syncthreads();
    }

    // ---- epilogue: two 64-row halves through LDS ----
    float* ep = (float*)lds;
    const int er = (lane >> 4) * 4;
    const int ec = lane & 15;
    constexpr int TPR = BN / 8;          // threads per row in pass 2
    constexpr int RPI = 256 / TPR;       // rows per iteration
    const int rl0  = tid / TPR;
    const int colb = (tid % TPR) * 8;

    // bias hoisted (constant across rows)
    float bv8[8];
    #pragma unroll
    for (int j = 0; j < 8; ++j) bv8[j] = bias[c0 + colb + j];

    #pragma unroll
    for (int h = 0; h < 2; ++h) {
        if (wr == h) {
            #pragma unroll
            for (int m = 0; m < 4; ++m)
                #pragma unroll
                for (int n = 0; n < NFC; ++n) {
                    const int col = wc * WN + n * 16 + ec;
                    #pragma unroll
                    for (int r = 0; r < 4; ++r)
                        ep[(m * 16 + er + r) * BN + col] = acc[m][n][r];
                }
        }
        __syncthreads();
        #pragma unroll
        for (int rr = 0; rr < 64 / RPI; ++rr) {
            const int rl = rr * RPI + rl0;
            const int grow = r0 + h * 64 + rl;
            f32x4 u0 = *(const f32x4*)(ep + rl * BN + colb);
            f32x4 u1 = *(const f32x4*)(ep + rl * BN + colb + 4);
            if (grow < N_NODES) {
                float v[8];
                #pragma unroll
                for (int j = 0; j < 4; ++j) { v[j] = u0[j] + bv8[j]; v[4 + j] = u1[j] + bv8[4 + j]; }
                const int gcol = c0 + colb;
                if constexpr (MODE == 0) {
                    uint4 p, q;
                    p.x = pk2(v[0], v[1]); p.y = pk2(v[2], v[3]);
                    p.z = pk2(v[4], v[5]); p.w = pk2(v[6], v[7]);
                    q.x = pk2(fmaxf(v[0], 0.f), fmaxf(v[1], 0.f));
                    q.y = pk2(fmaxf(v[2], 0.f), fmaxf(v[3], 0.f));
                    q.z = pk2(fmaxf(v[4], 0.f), fmaxf(v[5], 0.f));
                    q.w = pk2(fmaxf(v[6], 0.f), fmaxf(v[7], 0.f));
                    *(uint4*)(outb2 + (size_t)grow * HID + gcol) = p;
                    *(uint4*)(outb + (size_t)grow * HID + gcol) = q;
                } else if constexpr (MODE == 1) {
                    uint4 ip = *(const uint4*)(inp + (size_t)grow * HID + gcol);
                    float f[8];
                    unpack8(ip, f);
                    #pragma unroll
                    for (int j = 0; j < 8; ++j) v[j] = fmaxf(v[j], 0.f) + 0.2f * f[j];
                    uint4 q;
                    q.x = pk2(v[0], v[1]); q.y = pk2(v[2], v[3]);
                    q.z = pk2(v[4], v[5]); q.w = pk2(v[6], v[7]);
                    *(uint4*)(outb + (size_t)grow * HID + gcol) = q;
                } else {
                    *(float4*)(outf + (size_t)grow * 64 + gcol) =
                        make_float4(v[0], v[1], v[2], v[3]);
                    *(float4*)(outf + (size_t)grow * 64 + gcol + 4) =
                        make_float4(v[4], v[5], v[6], v[7]);
                }
            }
        }
        __syncthreads();
    }
}

// ---------------- in-place log_softmax over 64 cols, one wave per row ----------------
__global__ void lsm_k(float* __restrict__ out) {
    int r = blockIdx.x * 4 + (threadIdx.x >> 6);
    int lane = threadIdx.x & 63;
    if (r >= N_NODES) return;
    float v = out[(size_t)r * 64 + lane];
    float m = v;
    #pragma unroll
    for (int off = 32; off; off >>= 1) m = fmaxf(m, __shfl_xor(m, off));
    float s = expf(v - m);
    #pragma unroll
    for (int off = 32; off; off >>= 1) s += __shfl_xor(s, off);
    out[(size_t)r * 64 + lane] = (v - m) - logf(s);
}

extern "C" void kernel_launch(void* const* d_in, const int* in_sizes, int n_in,
                              void* d_out, int out_size, void* d_ws, size_t ws_size,
                              hipStream_t stream) {
    const float* x    = (const float*)d_in[0];
    const int*   ei   = (const int*)d_in[1];
    const float* W_in = (const float*)d_in[2];
    const float* b_in = (const float*)d_in[3];
    const float* Wl1  = (const float*)d_in[4];
    const float* bl1  = (const float*)d_in[5];
    const float* Wr1  = (const float*)d_in[6];
    const float* Wl2  = (const float*)d_in[7];
    const float* bl2  = (const float*)d_in[8];
    const float* Wr2  = (const float*)d_in[9];
    const float* Wl3  = (const float*)d_in[10];
    const float* bl3  = (const float*)d_in[11];
    const float* Wr3  = (const float*)d_in[12];
    float* out = (float*)d_out;

    const int* esrc = ei;
    const int* edst = ei + N_EDGES;

    char* ws = (char*)d_ws;
    u16* inp  = (u16*)(ws + 0);             // 51,200,000
    u16* xA   = (u16*)(ws + 51200000);      // 51,200,000
    u16* xB   = (u16*)(ws + 102400000);     // 51,200,000
    u16* mean = (u16*)(ws + 153600000);     // 51,200,000
    u16* xbf  = (u16*)(ws + 204800000);     // 25,600,000
    u16* BtIn = (u16*)(ws + 230400000);     // 65,536
    u16* Bt1  = (u16*)(ws + 230465536);     // 262,144
    u16* Bt2  = (u16*)(ws + 230727680);     // 262,144
    u16* Bt3  = (u16*)(ws + 230989824);     // 65,536
    int* icnt = (int*)(ws + 231055360);     // 400,000
    int* coff = (int*)(ws + 231455360);     // 400,000
    int* cpos = (int*)(ws + 231855360);     // 400,000
    int* csrc = (int*)(ws + 232255360);     // 1,200,000
    int* bsum = (int*)(ws + 233455360);     // 512

    dim3 blk(256);
    dim3 gE((N_EDGES + 255) / 256);
    dim3 gN((N_NODES + 255) / 256);
    dim3 gAgg((N_NODES + 7) / 8);
    dim3 gG2((N_NODES + 127) / 128, 2);     // 782 x 2
    dim3 gG1((N_NODES + 127) / 128, 1);     // 782 x 1

    // ---- CSR build ----
    hipMemsetAsync(icnt, 0, (size_t)N_NODES * 4, stream);
    icnt_k<<<gE, blk, 0, stream>>>(edst, icnt);
    scan1_k<<<NB_SCAN, blk, 0, stream>>>(icnt, coff, bsum);
    scan2_k<<<1, 128, 0, stream>>>(bsum);
    scan3_k<<<gN, blk, 0, stream>>>(coff, cpos, bsum);
    scat_k<<<gE, blk, 0, stream>>>(esrc, edst, cpos, csrc);

    // ---- conversions ----
    cvt_x_k<<<(N_NODES * 128 / 4 + 255) / 256, blk, 0, stream>>>(x, xbf);
    wt_k<<<(256 * 128 + 255) / 256, blk, 0, stream>>>(W_in, W_in, BtIn, 128, 7, 256, 256 * 128);
    wt_k<<<(256 * 512 + 255) / 256, blk, 0, stream>>>(Wl1, Wr1, Bt1, 256, 9, 256, 256 * 512);
    wt_k<<<(256 * 512 + 255) / 256, blk, 0, stream>>>(Wl2, Wr2, Bt2, 256, 9, 256, 256 * 512);
    wt_k<<<(64 * 512 + 255) / 256, blk, 0, stream>>>(Wl3, Wr3, Bt3, 256, 9, 64, 64 * 512);

    // ---- input: H0 = x @ W_in + b_in ; inp = H0, xA = relu(H0) ----
    mgemm_k<2, 2, 0, 128><<<gG2, blk, 0, stream>>>(
        xbf, xbf, 256, BtIn, b_in, nullptr, xA, inp, nullptr);

    // ---- layer 1 ----
    aggc_k<<<gAgg, blk, 0, stream>>>(xA, coff, cpos, csrc, mean);
    mgemm_k<8, 4, 1, 128><<<gG2, blk, 0, stream>>>(
        mean, xA, 512, Bt1, bl1, inp, xB, nullptr, nullptr);

    // ---- layer 2 ----
    aggc_k<<<gAgg, blk, 0, stream>>>(xB, coff, cpos, csrc, mean);
    mgemm_k<8, 4, 1, 128><<<gG2, blk, 0, stream>>>(
        mean, xB, 512, Bt2, bl2, inp, xA, nullptr, nullptr);

    // ---- layer 3 ----
    aggc_k<<<gAgg, blk, 0, stream>>>(xA, coff, cpos, csrc, mean);
    mgemm_k<8, 4, 2, 64><<<gG1, blk, 0, stream>>>(
        mean, xA, 512, Bt3, bl3, nullptr, nullptr, nullptr, out);

    // ---- log_softmax in place ----
    lsm_k<<<N_NODES / 4, blk, 0, stream>>>(out);
}

// Round 7
// 304.516 us; speedup vs baseline: 1.2835x; 1.1160x over previous
//
#include <hip/hip_runtime.h>
#include <hip/hip_bf16.h>
#include <stdint.h>

#define N_NODES 100000
#define N_EDGES 300000
#define HID 256
#define NB_SCAN 98   // ceil(100000/1024)

typedef unsigned short u16;
typedef unsigned int u32;
typedef __attribute__((ext_vector_type(8))) short short8;
typedef __attribute__((ext_vector_type(4))) float f32x4;

__device__ __forceinline__ float bf2f(u16 u) {
    union { u32 i; float f; } c; c.i = ((u32)u) << 16; return c.f;
}
__device__ __forceinline__ u16 f2bf(float f) {
    union { float f; u32 i; } c; c.f = f;
    u32 x = c.i;
    u32 r = (x + 0x7fffu + ((x >> 16) & 1u)) >> 16;  // round-nearest-even
    return (u16)r;
}
__device__ __forceinline__ u32 pk2(float lo, float hi) {
    return (u32)f2bf(lo) | ((u32)f2bf(hi) << 16);
}
__device__ __forceinline__ void unpack8(uint4 u, float* f) {
    f[0] = bf2f(u.x & 0xffffu); f[1] = bf2f(u.x >> 16);
    f[2] = bf2f(u.y & 0xffffu); f[3] = bf2f(u.y >> 16);
    f[4] = bf2f(u.z & 0xffffu); f[5] = bf2f(u.z >> 16);
    f[6] = bf2f(u.w & 0xffffu); f[7] = bf2f(u.w >> 16);
}

// bijective XCD-chunked swizzle (m204): XCD x gets a contiguous logical chunk
__device__ __forceinline__ int xcd_map(int orig, int nwg) {
    int q = nwg >> 3, r = nwg & 7;
    int x = orig & 7, i = orig >> 3;
    return (x < r ? x * (q + 1) : r * (q + 1) + (x - r) * q) + i;
}

// ---------------- CSR build ----------------
__global__ void icnt_k(const int* __restrict__ dst, int* __restrict__ icnt) {
    int e = blockIdx.x * blockDim.x + threadIdx.x;
    if (e < N_EDGES) atomicAdd(&icnt[dst[e]], 1);
}

__global__ void scan1_k(const int* __restrict__ icnt, int* __restrict__ off,
                        int* __restrict__ bsum) {
    __shared__ int sh[256];
    int t = threadIdx.x;
    int base = blockIdx.x * 1024 + t * 4;
    int v[4];
    #pragma unroll
    for (int j = 0; j < 4; ++j) {
        int idx = base + j;
        v[j] = (idx < N_NODES) ? icnt[idx] : 0;
    }
    int s = v[0] + v[1] + v[2] + v[3];
    sh[t] = s;
    __syncthreads();
    #pragma unroll
    for (int d = 1; d < 256; d <<= 1) {
        int x = (t >= d) ? sh[t - d] : 0;
        __syncthreads();
        if (t >= d) sh[t] += x;
        __syncthreads();
    }
    int excl = sh[t] - s;
    #pragma unroll
    for (int j = 0; j < 4; ++j) {
        int idx = base + j;
        if (idx < N_NODES) off[idx] = excl;
        excl += v[j];
    }
    if (t == 255) bsum[blockIdx.x] = sh[255];
}

__global__ void scan2_k(int* __restrict__ bsum) {
    __shared__ int sh[128];
    int t = threadIdx.x;
    int v = (t < NB_SCAN) ? bsum[t] : 0;
    sh[t] = v;
    __syncthreads();
    #pragma unroll
    for (int d = 1; d < 128; d <<= 1) {
        int x = (t >= d) ? sh[t - d] : 0;
        __syncthreads();
        if (t >= d) sh[t] += x;
        __syncthreads();
    }
    if (t < NB_SCAN) bsum[t] = sh[t] - v;
}

__global__ void scan3_k(int* __restrict__ off, int* __restrict__ pos,
                        const int* __restrict__ bsum) {
    int idx = blockIdx.x * blockDim.x + threadIdx.x;
    if (idx < N_NODES) {
        int o = off[idx] + bsum[idx >> 10];
        off[idx] = o;
        pos[idx] = o;
    }
}

__global__ void scat_k(const int* __restrict__ src, const int* __restrict__ dst,
                       int* __restrict__ pos, int* __restrict__ csrc) {
    int e = blockIdx.x * blockDim.x + threadIdx.x;
    if (e < N_EDGES) {
        int slot = atomicAdd(&pos[dst[e]], 1);
        csrc[slot] = src[e];
    }
}

// ---------------- CSR mean aggregation: 32 lanes per node ----------------
__global__ void aggc_k(const u16* __restrict__ x, const int* __restrict__ off,
                       const int* __restrict__ pos, const int* __restrict__ csrc,
                       u16* __restrict__ mean) {
    int node = blockIdx.x * (blockDim.x >> 5) + (threadIdx.x >> 5);
    if (node >= N_NODES) return;
    int lane = threadIdx.x & 31;
    int s = off[node], e = pos[node];
    float acc[8] = {0.f, 0.f, 0.f, 0.f, 0.f, 0.f, 0.f, 0.f};
    for (int i = s; i < e; ++i) {
        int sr = csrc[i];
        uint4 u = *(const uint4*)(x + (size_t)sr * HID + lane * 8);
        float f[8];
        unpack8(u, f);
        #pragma unroll
        for (int j = 0; j < 8; ++j) acc[j] += f[j];
    }
    float inv = 1.0f / fmaxf((float)(e - s), 1.0f);
    uint4 r;
    r.x = pk2(acc[0] * inv, acc[1] * inv);
    r.y = pk2(acc[2] * inv, acc[3] * inv);
    r.z = pk2(acc[4] * inv, acc[5] * inv);
    r.w = pk2(acc[6] * inv, acc[7] * inv);
    *(uint4*)(mean + (size_t)node * HID + lane * 8) = r;
}

// ---------------- conversions ----------------
__global__ void cvt_x_k(const float* __restrict__ x, u16* __restrict__ xb) {
    int i = blockIdx.x * blockDim.x + threadIdx.x;
    float4 v = ((const float4*)x)[i];
    uint2 r; r.x = pk2(v.x, v.y); r.y = pk2(v.z, v.w);
    ((uint2*)xb)[i] = r;
}

__global__ void wt_k(const float* __restrict__ Wl, const float* __restrict__ Wr,
                     u16* __restrict__ Bt, int K1, int LK, int N, int total) {
    int t = blockIdx.x * blockDim.x + threadIdx.x;
    if (t >= total) return;
    int n = t >> LK;
    int k = t & ((1 << LK) - 1);
    float v = (k < K1) ? Wl[(size_t)k * N + n] : Wr[(size_t)(k - K1) * N + n];
    Bt[t] = f2bf(v);
}

// ---------------- MFMA GEMM (256 thr, 32KB LDS, 2-barrier, XCD-paired) -----
// 1-D grid of 782*NCT blocks. Logical id = xcd_map(blockIdx.x): column-half is
// the fastest logical bit, so the NCT blocks sharing one A-panel are adjacent
// -> same XCD chunk -> second A read hits that XCD's L2.
// Tile 128 x BN, BK=64. 4 waves as 2(M) x 2(N).
// MODE 0: v=acc+bias; outb2=bf16(v), outb=bf16(relu(v)).
// MODE 1: v=relu(acc+bias)+0.2*inp; outb=bf16(v).
// MODE 2: v=acc+bias; outf[row*64+col]=log_softmax(v) (fused, row-complete).
template<int KC, int SPLIT, int MODE, int BN, int NCT>
__launch_bounds__(256, 4)
__global__ void mgemm_k(const u16* __restrict__ A1, const u16* __restrict__ A2,
                        int ldaB,
                        const u16* __restrict__ Bt,
                        const float* __restrict__ bias,
                        const u16* __restrict__ inp,
                        u16* __restrict__ outb, u16* __restrict__ outb2,
                        float* __restrict__ outf) {
    constexpr int WN  = BN / 2;          // cols per wave
    constexpr int NFC = WN / 16;         // 16-col frags per wave
    constexpr int ASZ = 128 * 128;       // A tile bytes (128 rows x 128B)
    constexpr int BSZ = BN * 128;        // B tile bytes
    constexpr int EPL = 64 * BN * 4;     // epilogue half-tile (f32)
    constexpr int LSZ = (ASZ + BSZ > EPL) ? (ASZ + BSZ) : EPL;
    constexpr int BI  = BN / 32;         // B issues per thread
    __shared__ char lds[LSZ];

    const int tid  = threadIdx.x;
    const int lane = tid & 63;
    const int wid  = tid >> 6;           // 0..3
    const int wr   = wid >> 1;           // M half
    const int wc   = wid & 1;            // N half
    const int lg   = xcd_map(blockIdx.x, gridDim.x);
    const int r0   = (lg / NCT) * 128;
    const int c0   = (lg % NCT) * BN;

    f32x4 acc[4][NFC];
    #pragma unroll
    for (int m = 0; m < 4; ++m)
        #pragma unroll
        for (int n = 0; n < NFC; ++n) acc[m][n] = (f32x4)(0.f);

    // pre-swizzled source slot: slot = (lane&7) ^ (row&7); row&7 == lane>>3
    const int sslot = (((lane & 7) ^ (lane >> 3)) << 4);
    const int lrow  = lane >> 3;

    for (int kc = 0; kc < KC; ++kc) {
        // ---- stage A tile [128 x 128B] : 4 issues/thread ----
        {
            const u16* Ag = (kc < SPLIT) ? A1 : A2;
            const int  kb = ((kc < SPLIT) ? kc : kc - SPLIT) * 128;
            #pragma unroll
            for (int i = 0; i < 4; ++i) {
                const int rb = wid * 32 + i * 8;
                int rg = r0 + rb + lrow;
                rg = (rg < N_NODES) ? rg : (N_NODES - 1);
                const char* g = (const char*)Ag + (size_t)rg * ldaB + kb + sslot;
                __builtin_amdgcn_global_load_lds(
                    (__attribute__((address_space(1))) void*)g,
                    (__attribute__((address_space(3))) void*)(lds + rb * 128),
                    16, 0, 0);
            }
        }
        // ---- stage B tile [BN x 128B] : BI issues/thread ----
        #pragma unroll
        for (int i = 0; i < BI; ++i) {
            const int nb = wid * (BN / 4) + i * 8;
            const int nt = c0 + nb + lrow;
            const char* g = (const char*)Bt + (size_t)nt * (KC * 128) + kc * 128 + sslot;
            __builtin_amdgcn_global_load_lds(
                (__attribute__((address_space(1))) void*)g,
                (__attribute__((address_space(3))) void*)(lds + ASZ + nb * 128),
                16, 0, 0);
        }
        __syncthreads();

        // ---- compute ----
        #pragma unroll
        for (int ks = 0; ks < 2; ++ks) {
            const int q = ((ks * 4 + (lane >> 4)) ^ (lane & 7)) << 4;
            short8 af[4], bv[NFC];
            #pragma unroll
            for (int m = 0; m < 4; ++m)
                af[m] = *(const short8*)(lds + (wr * 64 + m * 16 + (lane & 15)) * 128 + q);
            #pragma unroll
            for (int n = 0; n < NFC; ++n)
                bv[n] = *(const short8*)(lds + ASZ + (wc * WN + n * 16 + (lane & 15)) * 128 + q);
            #pragma unroll
            for (int m = 0; m < 4; ++m)
                #pragma unroll
                for (int n = 0; n < NFC; ++n)
                    acc[m][n] = __builtin_amdgcn_mfma_f32_16x16x32_bf16(
                        af[m], bv[n], acc[m][n], 0, 0, 0);
        }
        __syncthreads();
    }

    // ---- epilogue: two 64-row halves through LDS ----
    float* ep = (float*)lds;
    const int er = (lane >> 4) * 4;
    const int ec = lane & 15;
    constexpr int TPR = BN / 8;          // threads per row in pass 2
    constexpr int RPI = 256 / TPR;       // rows per iteration
    const int rl0  = tid / TPR;
    const int colb = (tid % TPR) * 8;

    float bv8[8];
    #pragma unroll
    for (int j = 0; j < 8; ++j) bv8[j] = bias[c0 + colb + j];

    #pragma unroll
    for (int h = 0; h < 2; ++h) {
        if (wr == h) {
            #pragma unroll
            for (int m = 0; m < 4; ++m)
                #pragma unroll
                for (int n = 0; n < NFC; ++n) {
                    const int col = wc * WN + n * 16 + ec;
                    #pragma unroll
                    for (int r = 0; r < 4; ++r)
                        ep[(m * 16 + er + r) * BN + col] = acc[m][n][r];
                }
        }
        __syncthreads();
        #pragma unroll
        for (int rr = 0; rr < 64 / RPI; ++rr) {
            const int rl = rr * RPI + rl0;
            const int grow = r0 + h * 64 + rl;
            f32x4 u0 = *(const f32x4*)(ep + rl * BN + colb);
            f32x4 u1 = *(const f32x4*)(ep + rl * BN + colb + 4);
            if (grow < N_NODES) {
                float v[8];
                #pragma unroll
                for (int j = 0; j < 4; ++j) { v[j] = u0[j] + bv8[j]; v[4 + j] = u1[j] + bv8[4 + j]; }
                const int gcol = c0 + colb;
                if constexpr (MODE == 0) {
                    uint4 p, q;
                    p.x = pk2(v[0], v[1]); p.y = pk2(v[2], v[3]);
                    p.z = pk2(v[4], v[5]); p.w = pk2(v[6], v[7]);
                    q.x = pk2(fmaxf(v[0], 0.f), fmaxf(v[1], 0.f));
                    q.y = pk2(fmaxf(v[2], 0.f), fmaxf(v[3], 0.f));
                    q.z = pk2(fmaxf(v[4], 0.f), fmaxf(v[5], 0.f));
                    q.w = pk2(fmaxf(v[6], 0.f), fmaxf(v[7], 0.f));
                    *(uint4*)(outb2 + (size_t)grow * HID + gcol) = p;
                    *(uint4*)(outb + (size_t)grow * HID + gcol) = q;
                } else if constexpr (MODE == 1) {
                    uint4 ip = *(const uint4*)(inp + (size_t)grow * HID + gcol);
                    float f[8];
                    unpack8(ip, f);
                    #pragma unroll
                    for (int j = 0; j < 8; ++j) v[j] = fmaxf(v[j], 0.f) + 0.2f * f[j];
                    uint4 q;
                    q.x = pk2(v[0], v[1]); q.y = pk2(v[2], v[3]);
                    q.z = pk2(v[4], v[5]); q.w = pk2(v[6], v[7]);
                    *(uint4*)(outb + (size_t)grow * HID + gcol) = q;
                } else {
                    // fused log_softmax over the 64-col row: 8 threads per row,
                    // consecutive tids -> same wave; reduce via shfl_xor 1,2,4.
                    float mx = v[0];
                    #pragma unroll
                    for (int j = 1; j < 8; ++j) mx = fmaxf(mx, v[j]);
                    #pragma unroll
                    for (int o2 = 1; o2 < 8; o2 <<= 1) mx = fmaxf(mx, __shfl_xor(mx, o2));
                    float se = 0.f;
                    #pragma unroll
                    for (int j = 0; j < 8; ++j) { v[j] -= mx; se += expf(v[j]); }
                    #pragma unroll
                    for (int o2 = 1; o2 < 8; o2 <<= 1) se += __shfl_xor(se, o2);
                    const float ls = logf(se);
                    *(float4*)(outf + (size_t)grow * 64 + gcol) =
                        make_float4(v[0] - ls, v[1] - ls, v[2] - ls, v[3] - ls);
                    *(float4*)(outf + (size_t)grow * 64 + gcol + 4) =
                        make_float4(v[4] - ls, v[5] - ls, v[6] - ls, v[7] - ls);
                }
            }
        }
        __syncthreads();
    }
}

extern "C" void kernel_launch(void* const* d_in, const int* in_sizes, int n_in,
                              void* d_out, int out_size, void* d_ws, size_t ws_size,
                              hipStream_t stream) {
    const float* x    = (const float*)d_in[0];
    const int*   ei   = (const int*)d_in[1];
    const float* W_in = (const float*)d_in[2];
    const float* b_in = (const float*)d_in[3];
    const float* Wl1  = (const float*)d_in[4];
    const float* bl1  = (const float*)d_in[5];
    const float* Wr1  = (const float*)d_in[6];
    const float* Wl2  = (const float*)d_in[7];
    const float* bl2  = (const float*)d_in[8];
    const float* Wr2  = (const float*)d_in[9];
    const float* Wl3  = (const float*)d_in[10];
    const float* bl3  = (const float*)d_in[11];
    const float* Wr3  = (const float*)d_in[12];
    float* out = (float*)d_out;

    const int* esrc = ei;
    const int* edst = ei + N_EDGES;

    char* ws = (char*)d_ws;
    u16* inp  = (u16*)(ws + 0);             // 51,200,000
    u16* xA   = (u16*)(ws + 51200000);      // 51,200,000
    u16* xB   = (u16*)(ws + 102400000);     // 51,200,000
    u16* mean = (u16*)(ws + 153600000);     // 51,200,000
    u16* xbf  = (u16*)(ws + 204800000);     // 25,600,000
    u16* BtIn = (u16*)(ws + 230400000);     // 65,536
    u16* Bt1  = (u16*)(ws + 230465536);     // 262,144
    u16* Bt2  = (u16*)(ws + 230727680);     // 262,144
    u16* Bt3  = (u16*)(ws + 230989824);     // 65,536
    int* icnt = (int*)(ws + 231055360);     // 400,000
    int* coff = (int*)(ws + 231455360);     // 400,000
    int* cpos = (int*)(ws + 231855360);     // 400,000
    int* csrc = (int*)(ws + 232255360);     // 1,200,000
    int* bsum = (int*)(ws + 233455360);     // 512

    dim3 blk(256);
    dim3 gE((N_EDGES + 255) / 256);
    dim3 gN((N_NODES + 255) / 256);
    dim3 gAgg((N_NODES + 7) / 8);
    const int NPR = (N_NODES + 127) / 128;  // 782 row-panels
    dim3 gG2(NPR * 2);                      // 1564, 1-D (pairs adjacent after map)
    dim3 gG1(NPR);

    // ---- CSR build ----
    hipMemsetAsync(icnt, 0, (size_t)N_NODES * 4, stream);
    icnt_k<<<gE, blk, 0, stream>>>(edst, icnt);
    scan1_k<<<NB_SCAN, blk, 0, stream>>>(icnt, coff, bsum);
    scan2_k<<<1, 128, 0, stream>>>(bsum);
    scan3_k<<<gN, blk, 0, stream>>>(coff, cpos, bsum);
    scat_k<<<gE, blk, 0, stream>>>(esrc, edst, cpos, csrc);

    // ---- conversions ----
    cvt_x_k<<<(N_NODES * 128 / 4 + 255) / 256, blk, 0, stream>>>(x, xbf);
    wt_k<<<(256 * 128 + 255) / 256, blk, 0, stream>>>(W_in, W_in, BtIn, 128, 7, 256, 256 * 128);
    wt_k<<<(256 * 512 + 255) / 256, blk, 0, stream>>>(Wl1, Wr1, Bt1, 256, 9, 256, 256 * 512);
    wt_k<<<(256 * 512 + 255) / 256, blk, 0, stream>>>(Wl2, Wr2, Bt2, 256, 9, 256, 256 * 512);
    wt_k<<<(64 * 512 + 255) / 256, blk, 0, stream>>>(Wl3, Wr3, Bt3, 256, 9, 64, 64 * 512);

    // ---- input: H0 = x @ W_in + b_in ; inp = H0, xA = relu(H0) ----
    mgemm_k<2, 2, 0, 128, 2><<<gG2, blk, 0, stream>>>(
        xbf, xbf, 256, BtIn, b_in, nullptr, xA, inp, nullptr);

    // ---- layer 1 ----
    aggc_k<<<gAgg, blk, 0, stream>>>(xA, coff, cpos, csrc, mean);
    mgemm_k<8, 4, 1, 128, 2><<<gG2, blk, 0, stream>>>(
        mean, xA, 512, Bt1, bl1, inp, xB, nullptr, nullptr);

    // ---- layer 2 ----
    aggc_k<<<gAgg, blk, 0, stream>>>(xB, coff, cpos, csrc, mean);
    mgemm_k<8, 4, 1, 128, 2><<<gG2, blk, 0, stream>>>(
        mean, xB, 512, Bt2, bl2, inp, xA, nullptr, nullptr);

    // ---- layer 3 (+ fused log_softmax) ----
    aggc_k<<<gAgg, blk, 0, stream>>>(xA, coff, cpos, csrc, mean);
    mgemm_k<8, 4, 2, 64, 1><<<gG1, blk, 0, stream>>>(
        mean, xA, 512, Bt3, bl3, nullptr, nullptr, nullptr, out);
}

// Round 8
// 293.626 us; speedup vs baseline: 1.3312x; 1.0371x over previous
//
#include <hip/hip_runtime.h>
#include <hip/hip_bf16.h>
#include <stdint.h>

#define N_NODES 100000
#define N_EDGES 300000
#define HID 256
#define NB_SCAN 98   // ceil(100000/1024)

typedef unsigned short u16;
typedef unsigned int u32;
typedef __attribute__((ext_vector_type(8))) short short8;
typedef __attribute__((ext_vector_type(4))) float f32x4;

__device__ __forceinline__ float bf2f(u16 u) {
    union { u32 i; float f; } c; c.i = ((u32)u) << 16; return c.f;
}
__device__ __forceinline__ u16 f2bf(float f) {
    union { float f; u32 i; } c; c.f = f;
    u32 x = c.i;
    u32 r = (x + 0x7fffu + ((x >> 16) & 1u)) >> 16;  // round-nearest-even
    return (u16)r;
}
__device__ __forceinline__ u32 pk2(float lo, float hi) {
    return (u32)f2bf(lo) | ((u32)f2bf(hi) << 16);
}
__device__ __forceinline__ void unpack8(uint4 u, float* f) {
    f[0] = bf2f(u.x & 0xffffu); f[1] = bf2f(u.x >> 16);
    f[2] = bf2f(u.y & 0xffffu); f[3] = bf2f(u.y >> 16);
    f[4] = bf2f(u.z & 0xffffu); f[5] = bf2f(u.z >> 16);
    f[6] = bf2f(u.w & 0xffffu); f[7] = bf2f(u.w >> 16);
}

// bijective XCD-chunked swizzle (m204): XCD x gets a contiguous logical chunk
__device__ __forceinline__ int xcd_map(int orig, int nwg) {
    int q = nwg >> 3, r = nwg & 7;
    int x = orig & 7, i = orig >> 3;
    return (x < r ? x * (q + 1) : r * (q + 1) + (x - r) * q) + i;
}

// ---------------- CSR build ----------------
__global__ void icnt_k(const int* __restrict__ dst, int* __restrict__ icnt) {
    int e = blockIdx.x * blockDim.x + threadIdx.x;
    if (e < N_EDGES) atomicAdd(&icnt[dst[e]], 1);
}

__global__ void scan1_k(const int* __restrict__ icnt, int* __restrict__ off,
                        int* __restrict__ bsum) {
    __shared__ int sh[256];
    int t = threadIdx.x;
    int base = blockIdx.x * 1024 + t * 4;
    int v[4];
    #pragma unroll
    for (int j = 0; j < 4; ++j) {
        int idx = base + j;
        v[j] = (idx < N_NODES) ? icnt[idx] : 0;
    }
    int s = v[0] + v[1] + v[2] + v[3];
    sh[t] = s;
    __syncthreads();
    #pragma unroll
    for (int d = 1; d < 256; d <<= 1) {
        int x = (t >= d) ? sh[t - d] : 0;
        __syncthreads();
        if (t >= d) sh[t] += x;
        __syncthreads();
    }
    int excl = sh[t] - s;
    #pragma unroll
    for (int j = 0; j < 4; ++j) {
        int idx = base + j;
        if (idx < N_NODES) off[idx] = excl;
        excl += v[j];
    }
    if (t == 255) bsum[blockIdx.x] = sh[255];
}

__global__ void scan2_k(int* __restrict__ bsum) {
    __shared__ int sh[128];
    int t = threadIdx.x;
    int v = (t < NB_SCAN) ? bsum[t] : 0;
    sh[t] = v;
    __syncthreads();
    #pragma unroll
    for (int d = 1; d < 128; d <<= 1) {
        int x = (t >= d) ? sh[t - d] : 0;
        __syncthreads();
        if (t >= d) sh[t] += x;
        __syncthreads();
    }
    if (t < NB_SCAN) bsum[t] = sh[t] - v;
}

__global__ void scan3_k(int* __restrict__ off, int* __restrict__ pos,
                        const int* __restrict__ bsum) {
    int idx = blockIdx.x * blockDim.x + threadIdx.x;
    if (idx < N_NODES) {
        int o = off[idx] + bsum[idx >> 10];
        off[idx] = o;
        pos[idx] = o;
    }
}

__global__ void scat_k(const int* __restrict__ src, const int* __restrict__ dst,
                       int* __restrict__ pos, int* __restrict__ csrc) {
    int e = blockIdx.x * blockDim.x + threadIdx.x;
    if (e < N_EDGES) {
        int slot = atomicAdd(&pos[dst[e]], 1);
        csrc[slot] = src[e];
    }
}

// ---------------- CSR mean aggregation: 32 lanes/node, 2-edge ILP ----------
__global__ void aggc_k(const u16* __restrict__ x, const int* __restrict__ off,
                       const int* __restrict__ pos, const int* __restrict__ csrc,
                       u16* __restrict__ mean) {
    int node = blockIdx.x * (blockDim.x >> 5) + (threadIdx.x >> 5);
    if (node >= N_NODES) return;
    int lane = threadIdx.x & 31;
    const u16* xp = x + lane * 8;
    int s = off[node], e = pos[node];
    float acc[8] = {0.f, 0.f, 0.f, 0.f, 0.f, 0.f, 0.f, 0.f};
    int i = s;
    for (; i + 2 <= e; i += 2) {
        int sr0 = csrc[i];
        int sr1 = csrc[i + 1];
        uint4 u0 = *(const uint4*)(xp + (size_t)sr0 * HID);
        uint4 u1 = *(const uint4*)(xp + (size_t)sr1 * HID);
        float f0[8], f1[8];
        unpack8(u0, f0);
        unpack8(u1, f1);
        #pragma unroll
        for (int j = 0; j < 8; ++j) acc[j] += f0[j] + f1[j];
    }
    if (i < e) {
        int sr = csrc[i];
        uint4 u = *(const uint4*)(xp + (size_t)sr * HID);
        float f[8];
        unpack8(u, f);
        #pragma unroll
        for (int j = 0; j < 8; ++j) acc[j] += f[j];
    }
    float inv = 1.0f / fmaxf((float)(e - s), 1.0f);
    uint4 r;
    r.x = pk2(acc[0] * inv, acc[1] * inv);
    r.y = pk2(acc[2] * inv, acc[3] * inv);
    r.z = pk2(acc[4] * inv, acc[5] * inv);
    r.w = pk2(acc[6] * inv, acc[7] * inv);
    *(uint4*)(mean + (size_t)node * HID + lane * 8) = r;
}

// ---------------- fused weight conversion (all 4 Bt buffers contiguous) ----
// out layout: BtIn[256][128] ++ Bt1[256][512] ++ Bt2[256][512] ++ Bt3[64][512]
__global__ void wtall_k(const float* __restrict__ W_in,
                        const float* __restrict__ Wl1, const float* __restrict__ Wr1,
                        const float* __restrict__ Wl2, const float* __restrict__ Wr2,
                        const float* __restrict__ Wl3, const float* __restrict__ Wr3,
                        u16* __restrict__ out) {
    int t = blockIdx.x * blockDim.x + threadIdx.x;
    if (t >= 327680) return;
    float v;
    if (t < 32768) {
        int n = t >> 7, k = t & 127;
        v = W_in[(size_t)k * 256 + n];
    } else if (t < 163840) {
        int t1 = t - 32768;
        int n = t1 >> 9, k = t1 & 511;
        v = (k < 256) ? Wl1[(size_t)k * 256 + n] : Wr1[(size_t)(k - 256) * 256 + n];
    } else if (t < 294912) {
        int t2 = t - 163840;
        int n = t2 >> 9, k = t2 & 511;
        v = (k < 256) ? Wl2[(size_t)k * 256 + n] : Wr2[(size_t)(k - 256) * 256 + n];
    } else {
        int t3 = t - 294912;
        int n = t3 >> 9, k = t3 & 511;
        v = (k < 256) ? Wl3[(size_t)k * 64 + n] : Wr3[(size_t)(k - 256) * 64 + n];
    }
    out[t] = f2bf(v);
}

// ---------------- MFMA GEMM (256 thr, 32KB LDS, 2-barrier, XCD-paired) -----
// 1-D grid of NPR*NCT blocks; xcd_map makes the NCT col-tiles sharing an
// A-panel adjacent -> same XCD L2.
// Tile 128 x BN, BK=64. 4 waves as 2(M) x 2(N).
// F32A: A1 is fp32 (row stride ldaB bytes); staged via reg-convert+ds_write
//       to the same swizzled LDS layout (only valid with KC==SPLIT).
// MODE 0: v=acc+bias; outb2=bf16(v), outb=bf16(relu(v)).
// MODE 1: v=relu(acc+bias)+0.2*inp; outb=bf16(v).
// MODE 2: v=acc+bias; outf[row*64+col]=log_softmax(v) (fused, row-complete).
template<int KC, int SPLIT, int MODE, int BN, int NCT, bool F32A>
__launch_bounds__(256, 4)
__global__ void mgemm_k(const u16* __restrict__ A1, const u16* __restrict__ A2,
                        int ldaB,
                        const u16* __restrict__ Bt,
                        const float* __restrict__ bias,
                        const u16* __restrict__ inp,
                        u16* __restrict__ outb, u16* __restrict__ outb2,
                        float* __restrict__ outf) {
    constexpr int WN  = BN / 2;          // cols per wave
    constexpr int NFC = WN / 16;         // 16-col frags per wave
    constexpr int ASZ = 128 * 128;       // A tile bytes (128 rows x 128B)
    constexpr int BSZ = BN * 128;        // B tile bytes
    constexpr int EPL = 64 * BN * 4;     // epilogue half-tile (f32)
    constexpr int LSZ = (ASZ + BSZ > EPL) ? (ASZ + BSZ) : EPL;
    constexpr int BI  = BN / 32;         // B issues per thread
    __shared__ char lds[LSZ];

    const int tid  = threadIdx.x;
    const int lane = tid & 63;
    const int wid  = tid >> 6;           // 0..3
    const int wr   = wid >> 1;           // M half
    const int wc   = wid & 1;            // N half
    const int lg   = xcd_map(blockIdx.x, gridDim.x);
    const int r0   = (lg / NCT) * 128;
    const int c0   = (lg % NCT) * BN;

    f32x4 acc[4][NFC];
    #pragma unroll
    for (int m = 0; m < 4; ++m)
        #pragma unroll
        for (int n = 0; n < NFC; ++n) acc[m][n] = (f32x4)(0.f);

    // swizzle: LDS[row][slot] = G[row][slot ^ (row&7)]; row&7 == lane>>3
    const int sidx  = (lane & 7) ^ (lane >> 3);   // pre-swizzled source slot idx
    const int lrow  = lane >> 3;

    for (int kc = 0; kc < KC; ++kc) {
        // ---- stage A tile [128 x 128B] ----
        if constexpr (F32A) {
            #pragma unroll
            for (int i = 0; i < 4; ++i) {
                const int rb = wid * 32 + i * 8;
                int rg = r0 + rb + lrow;
                rg = (rg < N_NODES) ? rg : (N_NODES - 1);
                const char* g = (const char*)A1 + (size_t)rg * ldaB + kc * 256 + sidx * 32;
                float4 f0 = *(const float4*)g;
                float4 f1 = *(const float4*)(g + 16);
                uint4 w;
                w.x = pk2(f0.x, f0.y); w.y = pk2(f0.z, f0.w);
                w.z = pk2(f1.x, f1.y); w.w = pk2(f1.z, f1.w);
                *(uint4*)(lds + (rb + lrow) * 128 + (lane & 7) * 16) = w;
            }
        } else {
            const u16* Ag = (kc < SPLIT) ? A1 : A2;
            const int  kb = ((kc < SPLIT) ? kc : kc - SPLIT) * 128;
            #pragma unroll
            for (int i = 0; i < 4; ++i) {
                const int rb = wid * 32 + i * 8;
                int rg = r0 + rb + lrow;
                rg = (rg < N_NODES) ? rg : (N_NODES - 1);
                const char* g = (const char*)Ag + (size_t)rg * ldaB + kb + sidx * 16;
                __builtin_amdgcn_global_load_lds(
                    (__attribute__((address_space(1))) void*)g,
                    (__attribute__((address_space(3))) void*)(lds + rb * 128),
                    16, 0, 0);
            }
        }
        // ---- stage B tile [BN x 128B] ----
        #pragma unroll
        for (int i = 0; i < BI; ++i) {
            const int nb = wid * (BN / 4) + i * 8;
            const int nt = c0 + nb + lrow;
            const char* g = (const char*)Bt + (size_t)nt * (KC * 128) + kc * 128 + sidx * 16;
            __builtin_amdgcn_global_load_lds(
                (__attribute__((address_space(1))) void*)g,
                (__attribute__((address_space(3))) void*)(lds + ASZ + nb * 128),
                16, 0, 0);
        }
        __syncthreads();

        // ---- compute ----
        #pragma unroll
        for (int ks = 0; ks < 2; ++ks) {
            const int q = ((ks * 4 + (lane >> 4)) ^ (lane & 7)) << 4;
            short8 af[4], bv[NFC];
            #pragma unroll
            for (int m = 0; m < 4; ++m)
                af[m] = *(const short8*)(lds + (wr * 64 + m * 16 + (lane & 15)) * 128 + q);
            #pragma unroll
            for (int n = 0; n < NFC; ++n)
                bv[n] = *(const short8*)(lds + ASZ + (wc * WN + n * 16 + (lane & 15)) * 128 + q);
            #pragma unroll
            for (int m = 0; m < 4; ++m)
                #pragma unroll
                for (int n = 0; n < NFC; ++n)
                    acc[m][n] = __builtin_amdgcn_mfma_f32_16x16x32_bf16(
                        af[m], bv[n], acc[m][n], 0, 0, 0);
        }
        __syncthreads();
    }

    // ---- epilogue: two 64-row halves through LDS ----
    float* ep = (float*)lds;
    const int er = (lane >> 4) * 4;
    const int ec = lane & 15;
    constexpr int TPR = BN / 8;          // threads per row in pass 2
    constexpr int RPI = 256 / TPR;       // rows per iteration
    const int rl0  = tid / TPR;
    const int colb = (tid % TPR) * 8;

    float bv8[8];
    #pragma unroll
    for (int j = 0; j < 8; ++j) bv8[j] = bias[c0 + colb + j];

    #pragma unroll
    for (int h = 0; h < 2; ++h) {
        if (wr == h) {
            #pragma unroll
            for (int m = 0; m < 4; ++m)
                #pragma unroll
                for (int n = 0; n < NFC; ++n) {
                    const int col = wc * WN + n * 16 + ec;
                    #pragma unroll
                    for (int r = 0; r < 4; ++r)
                        ep[(m * 16 + er + r) * BN + col] = acc[m][n][r];
                }
        }
        __syncthreads();
        #pragma unroll
        for (int rr = 0; rr < 64 / RPI; ++rr) {
            const int rl = rr * RPI + rl0;
            const int grow = r0 + h * 64 + rl;
            f32x4 u0 = *(const f32x4*)(ep + rl * BN + colb);
            f32x4 u1 = *(const f32x4*)(ep + rl * BN + colb + 4);
            if (grow < N_NODES) {
                float v[8];
                #pragma unroll
                for (int j = 0; j < 4; ++j) { v[j] = u0[j] + bv8[j]; v[4 + j] = u1[j] + bv8[4 + j]; }
                const int gcol = c0 + colb;
                if constexpr (MODE == 0) {
                    uint4 p, q;
                    p.x = pk2(v[0], v[1]); p.y = pk2(v[2], v[3]);
                    p.z = pk2(v[4], v[5]); p.w = pk2(v[6], v[7]);
                    q.x = pk2(fmaxf(v[0], 0.f), fmaxf(v[1], 0.f));
                    q.y = pk2(fmaxf(v[2], 0.f), fmaxf(v[3], 0.f));
                    q.z = pk2(fmaxf(v[4], 0.f), fmaxf(v[5], 0.f));
                    q.w = pk2(fmaxf(v[6], 0.f), fmaxf(v[7], 0.f));
                    *(uint4*)(outb2 + (size_t)grow * HID + gcol) = p;
                    *(uint4*)(outb + (size_t)grow * HID + gcol) = q;
                } else if constexpr (MODE == 1) {
                    uint4 ip = *(const uint4*)(inp + (size_t)grow * HID + gcol);
                    float f[8];
                    unpack8(ip, f);
                    #pragma unroll
                    for (int j = 0; j < 8; ++j) v[j] = fmaxf(v[j], 0.f) + 0.2f * f[j];
                    uint4 q;
                    q.x = pk2(v[0], v[1]); q.y = pk2(v[2], v[3]);
                    q.z = pk2(v[4], v[5]); q.w = pk2(v[6], v[7]);
                    *(uint4*)(outb + (size_t)grow * HID + gcol) = q;
                } else {
                    // fused log_softmax: 8 threads/row, shfl_xor 1,2,4
                    float mx = v[0];
                    #pragma unroll
                    for (int j = 1; j < 8; ++j) mx = fmaxf(mx, v[j]);
                    #pragma unroll
                    for (int o2 = 1; o2 < 8; o2 <<= 1) mx = fmaxf(mx, __shfl_xor(mx, o2));
                    float se = 0.f;
                    #pragma unroll
                    for (int j = 0; j < 8; ++j) { v[j] -= mx; se += expf(v[j]); }
                    #pragma unroll
                    for (int o2 = 1; o2 < 8; o2 <<= 1) se += __shfl_xor(se, o2);
                    const float ls = logf(se);
                    *(float4*)(outf + (size_t)grow * 64 + gcol) =
                        make_float4(v[0] - ls, v[1] - ls, v[2] - ls, v[3] - ls);
                    *(float4*)(outf + (size_t)grow * 64 + gcol + 4) =
                        make_float4(v[4] - ls, v[5] - ls, v[6] - ls, v[7] - ls);
                }
            }
        }
        __syncthreads();
    }
}

extern "C" void kernel_launch(void* const* d_in, const int* in_sizes, int n_in,
                              void* d_out, int out_size, void* d_ws, size_t ws_size,
                              hipStream_t stream) {
    const float* x    = (const float*)d_in[0];
    const int*   ei   = (const int*)d_in[1];
    const float* W_in = (const float*)d_in[2];
    const float* b_in = (const float*)d_in[3];
    const float* Wl1  = (const float*)d_in[4];
    const float* bl1  = (const float*)d_in[5];
    const float* Wr1  = (const float*)d_in[6];
    const float* Wl2  = (const float*)d_in[7];
    const float* bl2  = (const float*)d_in[8];
    const float* Wr2  = (const float*)d_in[9];
    const float* Wl3  = (const float*)d_in[10];
    const float* bl3  = (const float*)d_in[11];
    const float* Wr3  = (const float*)d_in[12];
    float* out = (float*)d_out;

    const int* esrc = ei;
    const int* edst = ei + N_EDGES;

    char* ws = (char*)d_ws;
    u16* inp  = (u16*)(ws + 0);             // 51,200,000
    u16* xA   = (u16*)(ws + 51200000);      // 51,200,000
    u16* xB   = (u16*)(ws + 102400000);     // 51,200,000
    u16* mean = (u16*)(ws + 153600000);     // 51,200,000
    u16* BtIn = (u16*)(ws + 230400000);     // 65,536   (Bt buffers contiguous)
    u16* Bt1  = (u16*)(ws + 230465536);     // 262,144
    u16* Bt2  = (u16*)(ws + 230727680);     // 262,144
    u16* Bt3  = (u16*)(ws + 230989824);     // 65,536
    int* icnt = (int*)(ws + 231055360);     // 400,000
    int* coff = (int*)(ws + 231455360);     // 400,000
    int* cpos = (int*)(ws + 231855360);     // 400,000
    int* csrc = (int*)(ws + 232255360);     // 1,200,000
    int* bsum = (int*)(ws + 233455360);     // 512

    dim3 blk(256);
    dim3 gE((N_EDGES + 255) / 256);
    dim3 gN((N_NODES + 255) / 256);
    dim3 gAgg((N_NODES + 7) / 8);
    const int NPR = (N_NODES + 127) / 128;  // 782 row-panels
    dim3 gG2(NPR * 2);
    dim3 gG1(NPR);

    // ---- CSR build ----
    hipMemsetAsync(icnt, 0, (size_t)N_NODES * 4, stream);
    icnt_k<<<gE, blk, 0, stream>>>(edst, icnt);
    scan1_k<<<NB_SCAN, blk, 0, stream>>>(icnt, coff, bsum);
    scan2_k<<<1, 128, 0, stream>>>(bsum);
    scan3_k<<<gN, blk, 0, stream>>>(coff, cpos, bsum);
    scat_k<<<gE, blk, 0, stream>>>(esrc, edst, cpos, csrc);

    // ---- weight conversions (one kernel) ----
    wtall_k<<<(327680 + 255) / 256, blk, 0, stream>>>(
        W_in, Wl1, Wr1, Wl2, Wr2, Wl3, Wr3, BtIn);

    // ---- input: H0 = x @ W_in + b_in ; inp = H0, xA = relu(H0) ----
    // A = x (f32, row stride 512B), staged with in-register convert.
    mgemm_k<2, 2, 0, 128, 2, true><<<gG2, blk, 0, stream>>>(
        (const u16*)x, nullptr, 512, BtIn, b_in, nullptr, xA, inp, nullptr);

    // ---- layer 1 ----
    aggc_k<<<gAgg, blk, 0, stream>>>(xA, coff, cpos, csrc, mean);
    mgemm_k<8, 4, 1, 128, 2, false><<<gG2, blk, 0, stream>>>(
        mean, xA, 512, Bt1, bl1, inp, xB, nullptr, nullptr);

    // ---- layer 2 ----
    aggc_k<<<gAgg, blk, 0, stream>>>(xB, coff, cpos, csrc, mean);
    mgemm_k<8, 4, 1, 128, 2, false><<<gG2, blk, 0, stream>>>(
        mean, xB, 512, Bt2, bl2, inp, xA, nullptr, nullptr);

    // ---- layer 3 (+ fused log_softmax) ----
    aggc_k<<<gAgg, blk, 0, stream>>>(xA, coff, cpos, csrc, mean);
    mgemm_k<8, 4, 2, 64, 1, false><<<gG1, blk, 0, stream>>>(
        mean, xA, 512, Bt3, bl3, nullptr, nullptr, nullptr, out);
}